// Round 7
// baseline (19560.443 us; speedup 1.0000x reference)
//
#include <hip/hip_runtime.h>
#include <hip/hip_bf16.h>
#include <stdint.h>

// LSTM: B=32, T=2048, I=256, H=512. torch gate order i,f,g,o.
// R7: remap-lite. R6 proved ws < 513MB (xg hoist impossible), so attack the
// LDS pipe, the largest in-loop serial term (~3900cy/step of the 8200):
//  (1) wave map (mi, gate) -> (mi, gate-pair, K-half): bfrag[2][12] = 96
//      VGPR (same as R0's 96), ONE A-read feeds 2 MFMAs -> A wave-reads
//      192 -> 96 per CU-step (-1150cy). K-half partials reduced with
//      ds_add_f32 into double-buffered g_ls (R1-proven-correct pattern;
//      zero + atomics cost ~+510cy) -> net ~-640cy.
//  (2) progressive h staging: LDS-write each polled word the moment its tag
//      matches, inside the poll loop -> ~770cy of ds_write_b32 moves into
//      the poll wait shadow, and hv[] liveness shrinks.
//  (3) __launch_bounds__(512,1): 1 block/CU -> 256-VGPR ceiling. Peak live
//      ~165 regs (bfrag 96 + hv<=32 + xv 16 + addr/state ~20). R1's spill
//      came from (512,2)'s 128 cap; VGPR_Count is this round's diagnostic.
// Poll scheme, publisher, x path, epilogue, barrier structure: byte-R0.

#define B_   32
#define T_   2048
#define I_   256
#define H_   512
#define NB   32          // recurrent blocks (one per 16 h-columns)
#define NTHR 512         // 8 waves
#define JC   16          // h-columns per block = H_/NB
#define KSL  12          // K-steps per K-half: 2 * 12 * 32 = 768 = H_+I_
#define SA   776         // padded LDS stride (uniform bank spread, proven)
#define NPAIR (B_ * H_ / 2)   // 8192 u64 words per slot

typedef __attribute__((ext_vector_type(8))) short short8;
typedef __attribute__((ext_vector_type(4))) float f32x4;

__device__ __forceinline__ unsigned short f2bf_bits(float v) {
    unsigned int u = __builtin_bit_cast(unsigned int, v);
    unsigned int r = (u + 0x7FFFu + ((u >> 16) & 1u)) >> 16;   // RNE
    return (unsigned short)r;
}
__device__ __forceinline__ float sigm(float x) {
    return 1.0f / (1.0f + __expf(-x));
}
__device__ __forceinline__ float tanh_fast(float x) {
    float e = __expf(2.0f * x);          // inf-safe: e=inf -> 1; e=0 -> -1
    return 1.0f - 2.0f / (e + 1.0f);
}

// hbuf word w: b = w>>8, bf16 cols (w&255)*2 .. +1. word = (pair<<32)|tag.
// Slot 0 gets (tag=0, h0); slot 1 poisoned (tag 0xFFFFFFFF never matches).
__global__ void lstm_init(const float* __restrict__ h0,
                          unsigned long long* __restrict__ hbuf) {
    int i = blockIdx.x * 256 + threadIdx.x;   // word index 0..NPAIR-1
    if (i < NPAIR) {
        const int b = i >> 8;                 // 256 pairs per batch row
        const int c = (i & 255) * 2;
        const unsigned lo = f2bf_bits(h0[b * H_ + c]);
        const unsigned hi = f2bf_bits(h0[b * H_ + c + 1]);
        const unsigned pair = lo | (hi << 16);
        hbuf[i] = ((unsigned long long)pair << 32) | 0u;   // tag 0
        hbuf[NPAIR + i] = 0xFFFFFFFFull;                   // poison slot 1
    }
}

__global__ __launch_bounds__(NTHR, 1) void lstm_persistent(
    const float* __restrict__ x,    // [B,T,I]
    const float* __restrict__ c0,   // [1,B,H]
    const float* __restrict__ Wih,  // [4H,I]
    const float* __restrict__ Whh,  // [4H,H]
    const float* __restrict__ bih,  // [4H]
    const float* __restrict__ bhh,  // [4H]
    float* __restrict__ out,        // result [B,T,H] ++ h_f [B,H] ++ c_f [B,H]
    unsigned long long* hbuf)       // [2][NPAIR] (tag | bf16-pair<<32)
{
    __shared__ __align__(16) unsigned short Als[B_][SA];  // A tile: [m][k] h|x
    __shared__ float g_ls[2][B_][4 * JC + 1];  // gate preacts, double-buffered

    const int tid  = threadIdx.x;
    const int bid  = blockIdx.x;
    const int lane = tid & 63;
    const int wave = tid >> 6;          // 0..7
    const int mi   = (wave & 1) * 16;   // batch-tile base (0 or 16)
    const int qp   = (wave >> 1) & 1;   // gate-pair: gates {2qp, 2qp+1}
    const int kh   = wave >> 2;         // K-half 0..1 (384 k each)
    const int l15  = lane & 15;
    const int kq8  = (lane >> 4) * 8;   // k sub-block within a 32-wide K step

    // ---- persistent B fragments: 2 gates x 12 K-steps = 96 VGPRs ----
    short8 bfrag[2][KSL];
#pragma unroll
    for (int gg = 0; gg < 2; ++gg) {
        const int grow = (qp * 2 + gg) * H_ + bid * JC + l15;  // gate row
#pragma unroll
        for (int s = 0; s < KSL; ++s) {
            const int k0 = kh * 384 + s * 32 + kq8;
            short8 f;
#pragma unroll
            for (int j = 0; j < 8; ++j) {
                const int k = k0 + j;
                const float v = (k < H_) ? Whh[(size_t)grow * H_ + k]
                                         : Wih[(size_t)grow * I_ + (k - H_)];
                f[j] = (short)f2bf_bits(v);
            }
            bfrag[gg][s] = f;
        }
    }

    // ---- per-thread epilogue state in registers ----
    const int eb   = tid >> 4;          // batch 0..31
    const int ejj  = tid & 15;          // column-in-block 0..15
    const int ecol = bid * JC + ejj;    // global h column
    float bias_i = bih[0 * H_ + ecol] + bhh[0 * H_ + ecol];
    float bias_f = bih[1 * H_ + ecol] + bhh[1 * H_ + ecol];
    float bias_g = bih[2 * H_ + ecol] + bhh[2 * H_ + ecol];
    float bias_o = bih[3 * H_ + ecol] + bhh[3 * H_ + ecol];
    float c_reg  = c0[eb * H_ + ecol];

    for (int t = 0; t < T_; ++t) {
        const int p = t & 1;

        // ---- issue x_t loads (HBM latency hides under the poll) ----
        float4 xv[4];
#pragma unroll
        for (int i = 0; i < 4; ++i) {
            const int idx = tid + i * NTHR;           // 0..2047 float4s
            const int m = idx >> 6, k4 = idx & 63;
            xv[i] = *(const float4*)(x + (size_t)m * T_ * I_ +
                                     (size_t)t * I_ + k4 * 4);
        }
        asm volatile("" ::: "memory");   // pin x-load issue before the poll

        // ---- zero this step's gate accumulator (buffer p; its previous
        //      users finished at step t-2, separated by bar1/bar2(t-1)) ----
        {
            float* gz = &g_ls[p][eb][0];
            gz[ejj] = 0.f; gz[JC + ejj] = 0.f;
            gz[2 * JC + ejj] = 0.f; gz[3 * JC + ejj] = 0.f;
        }

        // ---- poll h(t) with PROGRESSIVE staging: stage words the moment
        //      their tag matches (LDS writes hide in the poll wait) ----
        const unsigned tt = (unsigned)t;
        unsigned long long* hsrc = hbuf + (size_t)p * NPAIR;
        unsigned long long hv[16];
        unsigned need = 0xFFFFu;
        do {
#pragma unroll
            for (int i = 0; i < 16; ++i) {
                if (need & (1u << i)) {
                    hv[i] = __hip_atomic_load(&hsrc[tid + i * NTHR],
                                              __ATOMIC_RELAXED,
                                              __HIP_MEMORY_SCOPE_AGENT);
                }
            }
#pragma unroll
            for (int i = 0; i < 16; ++i) {
                if ((need & (1u << i)) && (unsigned)hv[i] == tt) {
                    const int j = tid + i * NTHR;     // word index
                    const int m = j >> 8;             // batch row
                    const int c = (j & 255) * 2;      // bf16 column
                    *(unsigned int*)&Als[m][c] = (unsigned int)(hv[i] >> 32);
                    need &= ~(1u << i);
                }
            }
        } while (need);

        // ---- convert & write x to LDS ----
#pragma unroll
        for (int i = 0; i < 4; ++i) {
            const int idx = tid + i * NTHR;
            const int m = idx >> 6, k4 = idx & 63;
            ushort4 pk;
            pk.x = f2bf_bits(xv[i].x); pk.y = f2bf_bits(xv[i].y);
            pk.z = f2bf_bits(xv[i].z); pk.w = f2bf_bits(xv[i].w);
            *(ushort4*)&Als[m][H_ + k4 * 4] = pk;
        }
        __syncthreads();                              // barrier #1

        // ---- partial gates over this wave's K-half: 1 A-read -> 2 MFMA ----
        f32x4 acc0 = {0.f, 0.f, 0.f, 0.f};
        f32x4 acc1 = {0.f, 0.f, 0.f, 0.f};
        const int mrow  = mi + l15;
        const int kbase = kh * 384 + kq8;
#pragma unroll
        for (int s = 0; s < KSL; ++s) {
            const short8 a = *(const short8*)&Als[mrow][kbase + s * 32];
            acc0 = __builtin_amdgcn_mfma_f32_16x16x32_bf16(a, bfrag[0][s], acc0, 0, 0, 0);
            acc1 = __builtin_amdgcn_mfma_f32_16x16x32_bf16(a, bfrag[1][s], acc1, 0, 0, 0);
        }
        // ---- reduce the 2 K-half partials: ds_add_f32 into g_ls[p] ----
        {
            const int r0 = mi + (lane >> 4) * 4;      // D: col=lane&15, row=r0+r
#pragma unroll
            for (int r = 0; r < 4; ++r) {
                atomicAdd(&g_ls[p][r0 + r][(qp * 2 + 0) * JC + l15], acc0[r]);
                atomicAdd(&g_ls[p][r0 + r][(qp * 2 + 1) * JC + l15], acc1[r]);
            }
        }
        __syncthreads();                              // barrier #2

        // ---- epilogue: one thread per (batch, column) ----
        const float* ge = &g_ls[p][eb][0];
        const float pi = ge[ejj]          + bias_i;
        const float pf = ge[JC + ejj]     + bias_f;
        const float pg = ge[2 * JC + ejj] + bias_g;
        const float po = ge[3 * JC + ejj] + bias_o;
        const float ig = sigm(pi), fg = sigm(pf);
        const float gg = tanh_fast(pg), og = sigm(po);
        c_reg = fg * c_reg + ig * gg;
        const float h = og * tanh_fast(c_reg);

        // ---- publish h(t+1): fire-and-forget tagged u64 ----
        const unsigned hvb = f2bf_bits(h);
        const unsigned nbv = __shfl_xor(hvb, 1);
        if ((ejj & 1) == 0) {
            const unsigned pair = hvb | (nbv << 16);
            const unsigned long long word =
                ((unsigned long long)pair << 32) | (unsigned)(t + 1);
            __hip_atomic_store(
                &hbuf[(size_t)((t + 1) & 1) * NPAIR + eb * 256 + (ecol >> 1)],
                word, __ATOMIC_RELAXED, __HIP_MEMORY_SCOPE_AGENT);
        }

        // ---- deferred HBM stores (off the recurrence critical path) ----
        out[(size_t)eb * T_ * H_ + (size_t)t * H_ + ecol] = h;
        if (t == T_ - 1) {
            out[(size_t)B_ * T_ * H_ + eb * H_ + ecol] = h;               // h_f
            out[(size_t)B_ * T_ * H_ + B_ * H_ + eb * H_ + ecol] = c_reg; // c_f
        }
        // No third barrier: Als writes (t+1) follow bar2(t) in program order
        // of every wave; all GEMM Als reads of t precede bar2(t). g_ls[p]
        // zeroing at t+2 is separated from epilogue reads (t) by bar1/bar2
        // of step t+1 (double buffer).
    }
}

extern "C" void kernel_launch(void* const* d_in, const int* in_sizes, int n_in,
                              void* d_out, int out_size, void* d_ws, size_t ws_size,
                              hipStream_t stream) {
    const float* x   = (const float*)d_in[0];
    const float* h0  = (const float*)d_in[1];
    const float* c0  = (const float*)d_in[2];
    const float* Wih = (const float*)d_in[3];
    const float* Whh = (const float*)d_in[4];
    const float* bih = (const float*)d_in[5];
    const float* bhh = (const float*)d_in[6];
    float* out = (float*)d_out;

    unsigned long long* hbuf = (unsigned long long*)d_ws;   // 2*8192*8 = 128 KB

    hipLaunchKernelGGL(lstm_init, dim3(32), dim3(256), 0, stream, h0, hbuf);
    hipLaunchKernelGGL(lstm_persistent, dim3(NB), dim3(NTHR), 0, stream,
                       x, c0, Wih, Whh, bih, bhh, out, hbuf);
}

// Round 8
// 10346.288 us; speedup vs baseline: 1.8906x; 1.8906x over previous
//
#include <hip/hip_runtime.h>
#include <hip/hip_bf16.h>
#include <stdint.h>

// LSTM: B=32, T=2048, I=256, H=512. torch gate order i,f,g,o.
// R8: producer/consumer WAVE SPECIALIZATION (R7 proved the compiler caps all
// waves at 128 VGPR -> any single-population design needing bfrag+hv+xv
// spills). 1024 threads, 16 waves:
//   waves 0-7  (GEMM):     bfrag Whh[16]+Wih[8] = 96 regs, acc 4. Never poll.
//   waves 8-15 (exchange): hv[16]=32 + xv=16 regs. Own poll/stage/epilogue/
//                          publish/c_reg -- geometry byte-identical to R0.
// Overlap: x-MFMAs(t+1) (no h dependence; x staged 1 step ahead into a
// double-buffered LDS tile) run between bar2(t) and bar1(t+1), i.e. UNDER
// the exchange waves' epilogue+publish+poll(t+1). Post-bar1 critical path
// drops from 24 MFMAs to 16 h-MFMAs (A-reads 192->128 b128).
// Sync: __syncthreads only (uniform counts in both branches) + R0's proven
// tagged-u64 agent-scope LLC exchange. No new memory-semantics assumptions.

#define B_   32
#define T_   2048
#define I_   256
#define H_   512
#define NB   32          // blocks (one per 16 h-columns)
#define NTHR 1024        // 16 waves
#define JC   16          // h-columns per block
#define KHH  16          // Whh K-steps (512/32)
#define KXX  8           // Wih K-steps (256/32)
#define SH   520         // Als_h ushort stride (1040B = 65 slots, ≡1 mod 8)
#define SX   264         // xb ushort stride   (528B  = 33 slots, ≡1 mod 8)
#define NPAIR (B_ * H_ / 2)   // 8192 u64 words per slot

typedef __attribute__((ext_vector_type(8))) short short8;
typedef __attribute__((ext_vector_type(4))) float f32x4;

__device__ __forceinline__ unsigned short f2bf_bits(float v) {
    unsigned int u = __builtin_bit_cast(unsigned int, v);
    unsigned int r = (u + 0x7FFFu + ((u >> 16) & 1u)) >> 16;   // RNE
    return (unsigned short)r;
}
__device__ __forceinline__ float sigm(float x) {
    return 1.0f / (1.0f + __expf(-x));
}
__device__ __forceinline__ float tanh_fast(float x) {
    float e = __expf(2.0f * x);          // inf-safe: e=inf -> 1; e=0 -> -1
    return 1.0f - 2.0f / (e + 1.0f);
}

// hbuf word w: b = w>>8, bf16 cols (w&255)*2 .. +1. word = (pair<<32)|tag.
// Slot 0 gets (tag=0, h0); slot 1 poisoned (tag 0xFFFFFFFF never matches).
__global__ void lstm_init(const float* __restrict__ h0,
                          unsigned long long* __restrict__ hbuf) {
    int i = blockIdx.x * 256 + threadIdx.x;   // word index 0..NPAIR-1
    if (i < NPAIR) {
        const int b = i >> 8;                 // 256 pairs per batch row
        const int c = (i & 255) * 2;
        const unsigned lo = f2bf_bits(h0[b * H_ + c]);
        const unsigned hi = f2bf_bits(h0[b * H_ + c + 1]);
        const unsigned pair = lo | (hi << 16);
        hbuf[i] = ((unsigned long long)pair << 32) | 0u;   // tag 0
        hbuf[NPAIR + i] = 0xFFFFFFFFull;                   // poison slot 1
    }
}

__global__ __launch_bounds__(NTHR, 1) void lstm_persistent(
    const float* __restrict__ x,    // [B,T,I]
    const float* __restrict__ c0,   // [1,B,H]
    const float* __restrict__ Wih,  // [4H,I]
    const float* __restrict__ Whh,  // [4H,H]
    const float* __restrict__ bih,  // [4H]
    const float* __restrict__ bhh,  // [4H]
    float* __restrict__ out,        // result [B,T,H] ++ h_f [B,H] ++ c_f [B,H]
    unsigned long long* hbuf)       // [2][NPAIR] (tag | bf16-pair<<32)
{
    __shared__ __align__(16) unsigned short Als[B_][SH];     // h tile  (33 KB)
    __shared__ __align__(16) unsigned short xb[2][B_][SX];   // x tiles (34 KB)
    __shared__ float g_ls[B_][4 * JC + 1];                   // gates   (8.3 KB)

    const int tid  = threadIdx.x;
    const int bid  = blockIdx.x;
    const int lane = tid & 63;
    const int wave = tid >> 6;          // 0..15
    const int l15  = lane & 15;
    const int kq8  = (lane >> 4) * 8;   // k sub-block within a 32-wide K step

    if (wave < 8) {
        // ==================== GEMM waves (0..7) ====================
        const int mi = (wave & 1) * 16;   // batch-tile base (0 or 16)
        const int q  = wave >> 1;         // gate index 0..3 == n-tile
        const int grow = q * H_ + bid * JC + l15;   // global gate row

        short8 bh[KHH];                   // Whh frags: 64 VGPRs
#pragma unroll
        for (int s = 0; s < KHH; ++s) {
            const int k0 = s * 32 + kq8;
            short8 f;
#pragma unroll
            for (int j = 0; j < 8; ++j)
                f[j] = (short)f2bf_bits(Whh[(size_t)grow * H_ + k0 + j]);
            bh[s] = f;
        }
        short8 bx[KXX];                   // Wih frags: 32 VGPRs
#pragma unroll
        for (int s = 0; s < KXX; ++s) {
            const int k0 = s * 32 + kq8;
            short8 f;
#pragma unroll
            for (int j = 0; j < 8; ++j)
                f[j] = (short)f2bf_bits(Wih[(size_t)grow * I_ + k0 + j]);
            bx[s] = f;
        }

        const int mrow = mi + l15;
        __syncthreads();                              // barP: xb[0] staged

        f32x4 acc = {0.f, 0.f, 0.f, 0.f};
#pragma unroll
        for (int s = 0; s < KXX; ++s) {               // x-partial for t=0
            const short8 a = *(const short8*)&xb[0][mrow][s * 32 + kq8];
            acc = __builtin_amdgcn_mfma_f32_16x16x32_bf16(a, bx[s], acc, 0, 0, 0);
        }
        __syncthreads();                              // bar1(0): h(0) staged

        for (int t = 0; t < T_; ++t) {
            // ---- h-GEMM: the only work on the post-bar1 critical path ----
#pragma unroll
            for (int s = 0; s < KHH; ++s) {
                const short8 a = *(const short8*)&Als[mrow][s * 32 + kq8];
                acc = __builtin_amdgcn_mfma_f32_16x16x32_bf16(a, bh[s], acc, 0, 0, 0);
            }
#pragma unroll
            for (int r = 0; r < 4; ++r) {             // D: col=l15, row=(lane>>4)*4+r
                g_ls[mi + (lane >> 4) * 4 + r][q * JC + l15] = acc[r];
            }
            __syncthreads();                          // bar2(t)

            // ---- x-partial for t+1 (overlaps epilogue+publish+poll) ----
            acc = (f32x4){0.f, 0.f, 0.f, 0.f};
            const unsigned short* xbuf = &xb[(t + 1) & 1][0][0];
#pragma unroll
            for (int s = 0; s < KXX; ++s) {
                const short8 a = *(const short8*)(xbuf + (size_t)mrow * SX +
                                                  s * 32 + kq8);
                acc = __builtin_amdgcn_mfma_f32_16x16x32_bf16(a, bx[s], acc, 0, 0, 0);
            }
            __syncthreads();                          // bar1(t+1): h(t+1) staged
        }
    } else {
        // ==================== exchange waves (8..15) ====================
        const int et   = tid - 512;         // 0..511, R0's thread geometry
        const int eb   = et >> 4;           // batch 0..31
        const int ejj  = et & 15;           // column-in-block
        const int ecol = bid * JC + ejj;    // global h column
        float bias_i = bih[0 * H_ + ecol] + bhh[0 * H_ + ecol];
        float bias_f = bih[1 * H_ + ecol] + bhh[1 * H_ + ecol];
        float bias_g = bih[2 * H_ + ecol] + bhh[2 * H_ + ecol];
        float bias_o = bih[3 * H_ + ecol] + bhh[3 * H_ + ecol];
        float c_reg  = c0[eb * H_ + ecol];

        float4 xv[4];
        // ---- prologue: stage x(0) -> xb[0] ----
#pragma unroll
        for (int i = 0; i < 4; ++i) {
            const int idx = et + i * 512;
            const int m = idx >> 6, k4 = idx & 63;
            xv[i] = *(const float4*)(x + (size_t)m * T_ * I_ + k4 * 4);
        }
#pragma unroll
        for (int i = 0; i < 4; ++i) {
            const int idx = et + i * 512;
            const int m = idx >> 6, k4 = idx & 63;
            ushort4 pk;
            pk.x = f2bf_bits(xv[i].x); pk.y = f2bf_bits(xv[i].y);
            pk.z = f2bf_bits(xv[i].z); pk.w = f2bf_bits(xv[i].w);
            *(ushort4*)&xb[0][m][k4 * 4] = pk;
        }
        __syncthreads();                              // barP

        // ---- prologue: x(1) issue, poll h(0), stage both ----
#pragma unroll
        for (int i = 0; i < 4; ++i) {
            const int idx = et + i * 512;
            const int m = idx >> 6, k4 = idx & 63;
            xv[i] = *(const float4*)(x + (size_t)m * T_ * I_ + (size_t)I_ + k4 * 4);
        }
        {
            unsigned long long hv[16];
            unsigned need = 0xFFFFu;
            do {
#pragma unroll
                for (int i = 0; i < 16; ++i)
                    if (need & (1u << i))
                        hv[i] = __hip_atomic_load(&hbuf[et + i * 512],
                                                  __ATOMIC_RELAXED,
                                                  __HIP_MEMORY_SCOPE_AGENT);
                unsigned ok = 0;
#pragma unroll
                for (int i = 0; i < 16; ++i)
                    if ((unsigned)hv[i] == 0u) ok |= (1u << i);
                need &= ~ok;
            } while (need);
#pragma unroll
            for (int i = 0; i < 16; ++i) {
                const int j = et + i * 512;
                const int m = j >> 8;
                const int c = (j & 255) * 2;
                *(unsigned int*)&Als[m][c] = (unsigned int)(hv[i] >> 32);
            }
        }
#pragma unroll
        for (int i = 0; i < 4; ++i) {
            const int idx = et + i * 512;
            const int m = idx >> 6, k4 = idx & 63;
            ushort4 pk;
            pk.x = f2bf_bits(xv[i].x); pk.y = f2bf_bits(xv[i].y);
            pk.z = f2bf_bits(xv[i].z); pk.w = f2bf_bits(xv[i].w);
            *(ushort4*)&xb[1][m][k4 * 4] = pk;
        }
        __syncthreads();                              // bar1(0)

        for (int t = 0; t < T_; ++t) {
            __syncthreads();                          // bar2(t)

            // ---- issue x(t+2) loads (land during the poll below) ----
            {
                const int tn = (t + 2 < T_) ? t + 2 : T_ - 1;
#pragma unroll
                for (int i = 0; i < 4; ++i) {
                    const int idx = et + i * 512;
                    const int m = idx >> 6, k4 = idx & 63;
                    xv[i] = *(const float4*)(x + (size_t)m * T_ * I_ +
                                             (size_t)tn * I_ + k4 * 4);
                }
            }

            // ---- epilogue + publish ASAP (other blocks are waiting) ----
            const float pi = g_ls[eb][ejj]          + bias_i;
            const float pf = g_ls[eb][JC + ejj]     + bias_f;
            const float pg = g_ls[eb][2 * JC + ejj] + bias_g;
            const float po = g_ls[eb][3 * JC + ejj] + bias_o;
            const float ig = sigm(pi), fg = sigm(pf);
            const float gg = tanh_fast(pg), og = sigm(po);
            c_reg = fg * c_reg + ig * gg;
            const float h = og * tanh_fast(c_reg);

            const unsigned hvb = f2bf_bits(h);
            const unsigned nbv = __shfl_xor(hvb, 1);
            if ((ejj & 1) == 0) {
                const unsigned pair = hvb | (nbv << 16);
                const unsigned long long word =
                    ((unsigned long long)pair << 32) | (unsigned)(t + 1);
                __hip_atomic_store(
                    &hbuf[(size_t)((t + 1) & 1) * NPAIR + eb * 256 + (ecol >> 1)],
                    word, __ATOMIC_RELAXED, __HIP_MEMORY_SCOPE_AGENT);
            }

            // ---- deferred HBM stores ----
            out[(size_t)eb * T_ * H_ + (size_t)t * H_ + ecol] = h;
            if (t == T_ - 1) {
                out[(size_t)B_ * T_ * H_ + eb * H_ + ecol] = h;               // h_f
                out[(size_t)B_ * T_ * H_ + B_ * H_ + eb * H_ + ecol] = c_reg; // c_f
            }

            // ---- poll h(t+1) (publishers: every block's step t) ----
            {
                const unsigned tt = (unsigned)(t + 1);
                unsigned long long* hsrc = hbuf + (size_t)((t + 1) & 1) * NPAIR;
                unsigned long long hv[16];
                unsigned need = 0xFFFFu;
                do {
#pragma unroll
                    for (int i = 0; i < 16; ++i)
                        if (need & (1u << i))
                            hv[i] = __hip_atomic_load(&hsrc[et + i * 512],
                                                      __ATOMIC_RELAXED,
                                                      __HIP_MEMORY_SCOPE_AGENT);
                    unsigned ok = 0;
#pragma unroll
                    for (int i = 0; i < 16; ++i)
                        if ((unsigned)hv[i] == tt) ok |= (1u << i);
                    need &= ~ok;
                } while (need);
#pragma unroll
                for (int i = 0; i < 16; ++i) {
                    const int j = et + i * 512;
                    const int m = j >> 8;
                    const int c = (j & 255) * 2;
                    *(unsigned int*)&Als[m][c] = (unsigned int)(hv[i] >> 32);
                }
            }

            // ---- stage x(t+2) -> xb[t&1] (its last readers finished the
            //      x-MFMAs for step t before bar1(t), behind us) ----
#pragma unroll
            for (int i = 0; i < 4; ++i) {
                const int idx = et + i * 512;
                const int m = idx >> 6, k4 = idx & 63;
                ushort4 pk;
                pk.x = f2bf_bits(xv[i].x); pk.y = f2bf_bits(xv[i].y);
                pk.z = f2bf_bits(xv[i].z); pk.w = f2bf_bits(xv[i].w);
                *(ushort4*)&xb[t & 1][m][k4 * 4] = pk;
            }
            __syncthreads();                          // bar1(t+1)
        }
    }
}

extern "C" void kernel_launch(void* const* d_in, const int* in_sizes, int n_in,
                              void* d_out, int out_size, void* d_ws, size_t ws_size,
                              hipStream_t stream) {
    const float* x   = (const float*)d_in[0];
    const float* h0  = (const float*)d_in[1];
    const float* c0  = (const float*)d_in[2];
    const float* Wih = (const float*)d_in[3];
    const float* Whh = (const float*)d_in[4];
    const float* bih = (const float*)d_in[5];
    const float* bhh = (const float*)d_in[6];
    float* out = (float*)d_out;

    unsigned long long* hbuf = (unsigned long long*)d_ws;   // 2*8192*8 = 128 KB

    hipLaunchKernelGGL(lstm_init, dim3(32), dim3(256), 0, stream, h0, hbuf);
    hipLaunchKernelGGL(lstm_persistent, dim3(NB), dim3(NTHR), 0, stream,
                       x, c0, Wih, Whh, bih, bhh, out, hbuf);
}